// Round 12
// baseline (21001.961 us; speedup 1.0000x reference)
//
#include <hip/hip_runtime.h>
#include <stdint.h>

typedef __bf16 bf16;
typedef __bf16 bf16x8 __attribute__((ext_vector_type(8)));
typedef float f32x4 __attribute__((ext_vector_type(4)));
typedef unsigned int u32x4 __attribute__((ext_vector_type(4)));

#define T_STEPS 2048

// ws layout (bytes)
static constexpr size_t OFF_XBF  = 0;                 // x bf16: 128 MB (dead after gemm; 32 flags reuse)
static constexpr size_t OFF_WIHB = 134217728;         // w_ih bf16 (gemm-only); h ping-pong (128 KB) reuses after gemm
static constexpr size_t OFF_WR   = 140509184;         // w_hh reordered bf16: 6 MB
static constexpr size_t OFF_GX   = 146800640;         // gx bf16 [t][g][48][32]: 384 MB
static constexpr size_t WS_NEED  = 549584960;

union PK8 { bf16 b[8]; uint4 u; };
union PK4 { bf16 b[4]; uint2 u; };

// ---------------- convert x to bf16 ----------------
__global__ void cvt_x_kernel(const float* __restrict__ x, bf16* __restrict__ xb) {
    size_t i = (size_t)blockIdx.x * 256 + threadIdx.x;   // 8 elements each, exact grid
    const float4* p = (const float4*)x + i * 2;
    float4 v0 = p[0], v1 = p[1];
    PK8 pk;
    pk.b[0]=(bf16)v0.x; pk.b[1]=(bf16)v0.y; pk.b[2]=(bf16)v0.z; pk.b[3]=(bf16)v0.w;
    pk.b[4]=(bf16)v1.x; pk.b[5]=(bf16)v1.y; pk.b[6]=(bf16)v1.z; pk.b[7]=(bf16)v1.w;
    ((uint4*)xb)[i] = pk.u;
}

// ---------------- convert w_ih, gather-reorder w_hh ----------------
__global__ void cvt_w_kernel(const float* __restrict__ wih, const float* __restrict__ whh,
                             bf16* __restrict__ wihb, bf16* __restrict__ wr) {
    int i = blockIdx.x * 256 + threadIdx.x;
    if (i < 786432) {                       // w_ih straight convert, 4 elems
        float4 v = ((const float4*)wih)[i];
        PK4 pk;
        pk.b[0]=(bf16)v.x; pk.b[1]=(bf16)v.y; pk.b[2]=(bf16)v.z; pk.b[3]=(bf16)v.w;
        ((uint2*)wihb)[i] = pk.u;
    } else {                                // w_hh -> wr[g][48][1024]; rows = {k16,f16,a16} of group g
        int d = (i - 786432) * 4;
        int g = d / 49152;
        int rem = d - g * 49152;
        int jr = rem >> 10, kk = rem & 1023;
        int srow = (jr >> 4) * 1024 + g * 16 + (jr & 15);
        float4 v = *(const float4*)(whh + (size_t)srow * 1024 + kk);
        PK4 pk;
        pk.b[0]=(bf16)v.x; pk.b[1]=(bf16)v.y; pk.b[2]=(bf16)v.z; pk.b[3]=(bf16)v.w;
        *(uint2*)(wr + d) = pk.u;
    }
}

// ---------------- gx = x @ w_ih^T + (b_ih+b_hh), bf16 MFMA, 128x128x32 tiles ----------------
__global__ __launch_bounds__(256) void gemm_x_kernel(
        const bf16* __restrict__ A, const bf16* __restrict__ W,
        const float* __restrict__ bih, const float* __restrict__ bhh,
        bf16* __restrict__ gx) {
    __shared__ bf16 a_s[128 * 40];   // +8 pad
    __shared__ bf16 b_s[128 * 40];
    const int tid = threadIdx.x;
    const int wave = tid >> 6, lane = tid & 63;
    const int wm = wave & 1, wn = wave >> 1;
    const int col = lane & 15, row0 = (lane >> 4) << 2, kq = (lane >> 4) << 3;
    const int m0 = blockIdx.x * 128, n0 = blockIdx.y * 128;
    const int r0 = tid >> 2, c0 = (tid & 3) << 3;
    const int r1 = r0 + 64;
    f32x4 acc[4][4];
    #pragma unroll
    for (int mi = 0; mi < 4; ++mi)
        #pragma unroll
        for (int ni = 0; ni < 4; ++ni) {
            acc[mi][ni][0] = 0.f; acc[mi][ni][1] = 0.f;
            acc[mi][ni][2] = 0.f; acc[mi][ni][3] = 0.f;
        }
    for (int kt = 0; kt < 32; ++kt) {
        const int k0 = kt * 32;
        uint4 va0 = *(const uint4*)(A + (size_t)(m0 + r0) * 1024 + k0 + c0);
        uint4 vb0 = *(const uint4*)(W + (size_t)(n0 + r0) * 1024 + k0 + c0);
        uint4 va1 = *(const uint4*)(A + (size_t)(m0 + r1) * 1024 + k0 + c0);
        uint4 vb1 = *(const uint4*)(W + (size_t)(n0 + r1) * 1024 + k0 + c0);
        __syncthreads();
        *(uint4*)(a_s + r0 * 40 + c0) = va0;
        *(uint4*)(b_s + r0 * 40 + c0) = vb0;
        *(uint4*)(a_s + r1 * 40 + c0) = va1;
        *(uint4*)(b_s + r1 * 40 + c0) = vb1;
        __syncthreads();
        bf16x8 af[4], bfv[4];
        #pragma unroll
        for (int i = 0; i < 4; ++i)
            af[i] = *(const bf16x8*)(a_s + (wm * 64 + i * 16 + col) * 40 + kq);
        #pragma unroll
        for (int i = 0; i < 4; ++i)
            bfv[i] = *(const bf16x8*)(b_s + (wn * 64 + i * 16 + col) * 40 + kq);
        #pragma unroll
        for (int mi = 0; mi < 4; ++mi)
            #pragma unroll
            for (int ni = 0; ni < 4; ++ni)
                acc[mi][ni] = __builtin_amdgcn_mfma_f32_16x16x32_bf16(af[mi], bfv[ni], acc[mi][ni], 0, 0, 0);
    }
    #pragma unroll
    for (int mi = 0; mi < 4; ++mi) {
        const int mbase = m0 + wm * 64 + mi * 16;
        const int t = mbase >> 5;
        const int b0 = (mbase & 31) + row0;
        #pragma unroll
        for (int ni = 0; ni < 4; ++ni) {
            const int n = n0 + wn * 64 + ni * 16 + col;
            const int gt = n >> 10, ii = n & 1023;
            const float bias = bih[n] + bhh[n];
            const size_t off = (((size_t)t * 64 + (ii >> 4)) * 48 + gt * 16 + (ii & 15)) * 32 + b0;
            f32x4 v = acc[mi][ni];
            PK4 pk;
            pk.b[0]=(bf16)(v[0]+bias); pk.b[1]=(bf16)(v[1]+bias);
            pk.b[2]=(bf16)(v[2]+bias); pk.b[3]=(bf16)(v[3]+bias);
            *(uint2*)(gx + off) = pk.u;
        }
    }
}

// ---------------- persistent recurrent kernel ----------------
// 32 WGs x 768 thr (12 waves = 2 mtiles x 6 ntiles). 2 feature-groups per WG:
// halves the grid-wide coherent h-broadcast (2 MB/step) and doubles per-CU
// outstanding coherent loads. Untagged bf16 exchange + per-WG flag array
// (R1's proven protocol: publish -> vmcnt(0) -> sync -> flag; wave0 polls).
__global__ __launch_bounds__(768, 1) void smru_rec_kernel(
        const bf16* __restrict__ wr, const bf16* __restrict__ gx,
        const float* __restrict__ h0,
        bf16* __restrict__ hbuf, float* __restrict__ out,
        unsigned int* __restrict__ flags) {
    extern __shared__ char smem[];
    bf16* h_s = (bf16*)smem;               // 2 x 32x512 bf16 = 65536 B (swizzled)
    float* g_s = (float*)(smem + 65536);   // 12 tiles x 16x17 fp32 = 13056 B
    const int g2 = blockIdx.x;             // pair index: groups 2*g2, 2*g2+1
    const int tid = threadIdx.x;
    const int wave = tid >> 6, lane = tid & 63;
    const int mtile = wave & 1, ntile = wave >> 1;   // ntile 0..5 = glocal*3 + gate
    const int glocal = ntile / 3, gate = ntile % 3;
    const int g = g2 * 2 + glocal;
    const int col = lane & 15, row0 = (lane >> 4) << 2, kq = (lane >> 4) << 3;
    const int f0 = g2 << 5;

    // ---- weights into registers: B-fragment rows (gate*16+col of group g), K=1024 ----
    bf16x8 wreg[32];
    {
        const bf16* wrow = wr + (size_t)g * 49152 + (size_t)(gate * 16 + col) * 1024 + kq;
        #pragma unroll
        for (int c2 = 0; c2 < 2; ++c2)
            #pragma unroll
            for (int kk = 0; kk < 16; ++kk)
                wreg[c2 * 16 + kk] = *(const bf16x8*)(wrow + c2 * 512 + kk * 32);
    }

    // fp32 recurrent state in registers: (batch, feature) per thread
    const int il = tid & 31;               // feature within the 32-feature pair
    const int b1 = tid >> 5;               // batch rows 0..23
    const int b2 = 24 + (tid >> 5);        // batch rows 24..31, valid when tid<256
    float h1 = h0[b1 * 1024 + f0 + il];
    float h2 = (tid < 256) ? h0[b2 * 1024 + f0 + il] : 0.f;

    const int hrow = mtile * 16 + col;
    const int hswz = (hrow & 7) * 8;

    // preload gx for t=0
    uint2 gv = *(const uint2*)(gx + (((size_t)0 * 64 + g) * 48 + gate * 16 + col) * 32
                               + mtile * 16 + row0);

    for (int t = 0; t < T_STEPS; ++t) {
        // ================= stage h_t into LDS =================
        if (t == 0) {
            // seed directly from fp32 h0 (no poll); 4096 16B-units over 768 thr
            #pragma unroll
            for (int j = 0; j < 6; ++j) {
                if (j < 5 || tid < 256) {
                    int s = tid + 768 * j;
                    int r = s >> 7, c8 = (s & 127) << 3;
                    float4 f0v = *(const float4*)(h0 + r * 1024 + c8);
                    float4 f1v = *(const float4*)(h0 + r * 1024 + c8 + 4);
                    PK8 pk;
                    pk.b[0]=(bf16)f0v.x; pk.b[1]=(bf16)f0v.y; pk.b[2]=(bf16)f0v.z; pk.b[3]=(bf16)f0v.w;
                    pk.b[4]=(bf16)f1v.x; pk.b[5]=(bf16)f1v.y; pk.b[6]=(bf16)f1v.z; pk.b[7]=(bf16)f1v.w;
                    int hf = c8 >> 9, cc = c8 & 511;
                    *(uint4*)(h_s + hf * 16384 + r * 512 + (cc ^ ((r & 7) * 8))) = pk.u;
                }
            }
        } else {
            const bf16* hsrc = hbuf + (size_t)(t & 1) * 32768;
            // issue ALL coherent loads up front (max outstanding), then drain once
            u32x4 L0[3], L1[3];
            #pragma unroll
            for (int j = 0; j < 3; ++j) {
                if (j < 2 || tid < 512) {
                    int s = tid + 768 * j;
                    int r = s >> 6, c8 = (s & 63) << 3;
                    const bf16* p = hsrc + r * 1024 + c8;
                    asm volatile("global_load_dwordx4 %0, %1, off sc0 sc1"
                                 : "=v"(L0[j]) : "v"(p) : "memory");
                }
            }
            #pragma unroll
            for (int j = 0; j < 3; ++j) {
                if (j < 2 || tid < 512) {
                    int s = tid + 768 * j;
                    int r = s >> 6, c8 = (s & 63) << 3;
                    const bf16* p = hsrc + r * 1024 + 512 + c8;
                    asm volatile("global_load_dwordx4 %0, %1, off sc0 sc1"
                                 : "=v"(L1[j]) : "v"(p) : "memory");
                }
            }
            asm volatile("s_waitcnt vmcnt(0)" ::: "memory");
            __builtin_amdgcn_sched_barrier(0);
            #pragma unroll
            for (int j = 0; j < 3; ++j) {
                if (j < 2 || tid < 512) {
                    int s = tid + 768 * j;
                    int r = s >> 6, c8 = (s & 63) << 3;
                    *(u32x4*)(h_s + r * 512 + (c8 ^ ((r & 7) * 8))) = L0[j];
                    *(u32x4*)(h_s + 16384 + r * 512 + (c8 ^ ((r & 7) * 8))) = L1[j];
                }
            }
        }

        // prefetch gx for t+1 (normal cached load)
        uint2 gvn;
        {
            int tn = (t + 1 < T_STEPS) ? t + 1 : t;
            gvn = *(const uint2*)(gx + (((size_t)tn * 64 + g) * 48 + gate * 16 + col) * 32
                                  + mtile * 16 + row0);
        }

        __syncthreads();   // sync A: h_s ready; also orders g_s reuse vs prior softmax

        // acc init from gx; second accumulator breaks the MFMA dep chain
        f32x4 acc, acc2;
        {
            union { uint2 u; bf16 b[4]; } pk; pk.u = gv;
            acc[0] = (float)pk.b[0]; acc[1] = (float)pk.b[1];
            acc[2] = (float)pk.b[2]; acc[3] = (float)pk.b[3];
            acc2[0] = 0.f; acc2[1] = 0.f; acc2[2] = 0.f; acc2[3] = 0.f;
        }

        const bf16* hb0 = h_s + hrow * 512;
        const bf16* hb1 = h_s + 16384 + hrow * 512;
        #pragma unroll
        for (int kk = 0; kk < 8; ++kk) {
            bf16x8 a0 = *(const bf16x8*)(hb0 + ((kk * 32 + kq) ^ hswz));
            bf16x8 a1 = *(const bf16x8*)(hb0 + (((kk + 8) * 32 + kq) ^ hswz));
            acc  = __builtin_amdgcn_mfma_f32_16x16x32_bf16(a0, wreg[kk], acc, 0, 0, 0);
            acc2 = __builtin_amdgcn_mfma_f32_16x16x32_bf16(a1, wreg[kk + 8], acc2, 0, 0, 0);
        }
        #pragma unroll
        for (int kk = 0; kk < 8; ++kk) {
            bf16x8 a0 = *(const bf16x8*)(hb1 + ((kk * 32 + kq) ^ hswz));
            bf16x8 a1 = *(const bf16x8*)(hb1 + (((kk + 8) * 32 + kq) ^ hswz));
            acc  = __builtin_amdgcn_mfma_f32_16x16x32_bf16(a0, wreg[16 + kk], acc, 0, 0, 0);
            acc2 = __builtin_amdgcn_mfma_f32_16x16x32_bf16(a1, wreg[24 + kk], acc2, 0, 0, 0);
        }

        // ---- gate exchange (stride-17 pad); tile = ntile*2 + mtile ----
        float* gw = g_s + (ntile * 2 + mtile) * 272;
        gw[(row0 + 0) * 17 + col] = acc[0] + acc2[0];
        gw[(row0 + 1) * 17 + col] = acc[1] + acc2[1];
        gw[(row0 + 2) * 17 + col] = acc[2] + acc2[2];
        gw[(row0 + 3) * 17 + col] = acc[3] + acc2[3];
        __syncthreads();   // sync B

        // ---- softmax + state update ----
        bf16* hdst = hbuf + (size_t)((t + 1) & 1) * 32768;
        const int gb = (il >> 4) * 6;      // glocal*6
        const int ic = il & 15;
        float hy1, hy2 = 0.f;
        {
            const int mt = b1 >> 4, rw = b1 & 15;
            const float gk = g_s[(gb + 0 + mt) * 272 + rw * 17 + ic];
            const float gf = g_s[(gb + 2 + mt) * 272 + rw * 17 + ic];
            const float ga = g_s[(gb + 4 + mt) * 272 + rw * 17 + ic];
            const float mx = fmaxf(gk, fmaxf(gf, ga));
            const float ek = __expf(gk - mx), ef = __expf(gf - mx), ea = __expf(ga - mx);
            const float inv = 1.0f / (ek + ef + ea);
            hy1 = ek * inv * h1 + ea * inv;
            h1 = hy1;
        }
        // paired agent stores of next-h (even il stores 2xbf16 as u32)
        {
            union { bf16 h; unsigned short u; } cv; cv.h = (bf16)hy1;
            unsigned int nb = __shfl_down((unsigned int)cv.u, 1);
            if ((il & 1) == 0)
                __hip_atomic_store((unsigned int*)(hdst + b1 * 1024 + f0 + il),
                                   (unsigned int)cv.u | (nb << 16),
                                   __ATOMIC_RELAXED, __HIP_MEMORY_SCOPE_AGENT);
        }
        if (tid < 256) {                   // batch rows 24..31
            const int mt = b2 >> 4, rw = b2 & 15;
            const float gk = g_s[(gb + 0 + mt) * 272 + rw * 17 + ic];
            const float gf = g_s[(gb + 2 + mt) * 272 + rw * 17 + ic];
            const float ga = g_s[(gb + 4 + mt) * 272 + rw * 17 + ic];
            const float mx = fmaxf(gk, fmaxf(gf, ga));
            const float ek = __expf(gk - mx), ef = __expf(gf - mx), ea = __expf(ga - mx);
            const float inv = 1.0f / (ek + ef + ea);
            hy2 = ek * inv * h2 + ea * inv;
            h2 = hy2;
            union { bf16 h; unsigned short u; } cv2; cv2.h = (bf16)hy2;
            unsigned int nb2 = __shfl_down((unsigned int)cv2.u, 1);
            if ((il & 1) == 0)
                __hip_atomic_store((unsigned int*)(hdst + b2 * 1024 + f0 + il),
                                   (unsigned int)cv2.u | (nb2 << 16),
                                   __ATOMIC_RELAXED, __HIP_MEMORY_SCOPE_AGENT);
        }

        // ---- release: own coherent stores drained -> WG sync -> flag ----
        asm volatile("s_waitcnt vmcnt(0)" ::: "memory");
        __syncthreads();   // sync C
        if (tid == 0)
            __hip_atomic_store(flags + g2, (unsigned int)(t + 1),
                               __ATOMIC_RELAXED, __HIP_MEMORY_SCOPE_AGENT);

        // out stores off the critical path (normal cached stores)
        out[((size_t)t * 32 + b1) * 1024 + f0 + il] = hy1;
        if (tid < 256) out[((size_t)t * 32 + b2) * 1024 + f0 + il] = hy2;

        gv = gvn;

        // ---- wait: wave0 polls all 32 flags in one wave-load; barrier releases ----
        if (t + 1 < T_STEPS) {
            const unsigned int tgt = (unsigned int)(t + 1);
            if (tid < 64) {
                for (;;) {
                    unsigned int f = __hip_atomic_load(flags + (tid & 31),
                        __ATOMIC_RELAXED, __HIP_MEMORY_SCOPE_AGENT);
                    if (__all((int)(f >= tgt))) break;
                }
            }
            __syncthreads();   // sync D
            asm volatile("" ::: "memory");
        }
    }
}

extern "C" void kernel_launch(void* const* d_in, const int* in_sizes, int n_in,
                              void* d_out, int out_size, void* d_ws, size_t ws_size,
                              hipStream_t stream) {
    const float* x   = (const float*)d_in[0];
    const float* h0  = (const float*)d_in[1];
    const float* wih = (const float*)d_in[2];
    const float* whh = (const float*)d_in[3];
    const float* bih = (const float*)d_in[4];
    const float* bhh = (const float*)d_in[5];
    float* out = (float*)d_out;
    char* ws = (char*)d_ws;
    if (ws_size < WS_NEED) return;

    bf16* xb   = (bf16*)(ws + OFF_XBF);
    bf16* wihb = (bf16*)(ws + OFF_WIHB);
    bf16* wrp  = (bf16*)(ws + OFF_WR);
    bf16* gx   = (bf16*)(ws + OFF_GX);
    bf16* hbuf = (bf16*)(ws + OFF_WIHB);                 // wihb dead after gemm
    unsigned int* flags = (unsigned int*)(ws + OFF_XBF); // xb dead after gemm

    cvt_x_kernel<<<32768, 256, 0, stream>>>(x, xb);
    cvt_w_kernel<<<6144, 256, 0, stream>>>(wih, whh, wihb, wrp);
    gemm_x_kernel<<<dim3(512, 24), 256, 0, stream>>>(xb, wihb, bih, bhh, gx);
    hipMemsetAsync(flags, 0, 128, stream);               // after gemm reads xb
    hipFuncSetAttribute((const void*)smru_rec_kernel,
                        hipFuncAttributeMaxDynamicSharedMemorySize, 78592);
    smru_rec_kernel<<<32, 768, 78592, stream>>>(wrp, gx, h0, hbuf, out, flags);
}

// Round 13
// 15424.698 us; speedup vs baseline: 1.3616x; 1.3616x over previous
//
#include <hip/hip_runtime.h>
#include <stdint.h>

typedef __bf16 bf16;
typedef __bf16 bf16x8 __attribute__((ext_vector_type(8)));
typedef float f32x4 __attribute__((ext_vector_type(4)));
typedef unsigned int u32x4 __attribute__((ext_vector_type(4)));

#define T_STEPS 2048

// ws layout (bytes)
static constexpr size_t OFF_XBF  = 0;                 // x bf16: 128 MB (dead after gemm; 32 flags reuse)
static constexpr size_t OFF_WIHB = 134217728;         // w_ih bf16 (gemm-only); h ping-pong (128 KB) reuses after gemm
static constexpr size_t OFF_WR   = 140509184;         // w_hh reordered bf16: 6 MB
static constexpr size_t OFF_GX   = 146800640;         // gx bf16 [t][g][48][32]: 384 MB
static constexpr size_t WS_NEED  = 549584960;

union PK8 { bf16 b[8]; uint4 u; };
union PK4 { bf16 b[4]; uint2 u; };

// ---------------- convert x to bf16 ----------------
__global__ void cvt_x_kernel(const float* __restrict__ x, bf16* __restrict__ xb) {
    size_t i = (size_t)blockIdx.x * 256 + threadIdx.x;   // 8 elements each, exact grid
    const float4* p = (const float4*)x + i * 2;
    float4 v0 = p[0], v1 = p[1];
    PK8 pk;
    pk.b[0]=(bf16)v0.x; pk.b[1]=(bf16)v0.y; pk.b[2]=(bf16)v0.z; pk.b[3]=(bf16)v0.w;
    pk.b[4]=(bf16)v1.x; pk.b[5]=(bf16)v1.y; pk.b[6]=(bf16)v1.z; pk.b[7]=(bf16)v1.w;
    ((uint4*)xb)[i] = pk.u;
}

// ---------------- convert w_ih, gather-reorder w_hh ----------------
__global__ void cvt_w_kernel(const float* __restrict__ wih, const float* __restrict__ whh,
                             bf16* __restrict__ wihb, bf16* __restrict__ wr) {
    int i = blockIdx.x * 256 + threadIdx.x;
    if (i < 786432) {                       // w_ih straight convert, 4 elems
        float4 v = ((const float4*)wih)[i];
        PK4 pk;
        pk.b[0]=(bf16)v.x; pk.b[1]=(bf16)v.y; pk.b[2]=(bf16)v.z; pk.b[3]=(bf16)v.w;
        ((uint2*)wihb)[i] = pk.u;
    } else {                                // w_hh -> wr[g][48][1024]; rows = {k16,f16,a16} of group g
        int d = (i - 786432) * 4;
        int g = d / 49152;
        int rem = d - g * 49152;
        int jr = rem >> 10, kk = rem & 1023;
        int srow = (jr >> 4) * 1024 + g * 16 + (jr & 15);
        float4 v = *(const float4*)(whh + (size_t)srow * 1024 + kk);
        PK4 pk;
        pk.b[0]=(bf16)v.x; pk.b[1]=(bf16)v.y; pk.b[2]=(bf16)v.z; pk.b[3]=(bf16)v.w;
        *(uint2*)(wr + d) = pk.u;
    }
}

// ---------------- gx = x @ w_ih^T + (b_ih+b_hh), bf16 MFMA, 128x128x32 tiles ----------------
__global__ __launch_bounds__(256) void gemm_x_kernel(
        const bf16* __restrict__ A, const bf16* __restrict__ W,
        const float* __restrict__ bih, const float* __restrict__ bhh,
        bf16* __restrict__ gx) {
    __shared__ bf16 a_s[128 * 40];   // +8 pad
    __shared__ bf16 b_s[128 * 40];
    const int tid = threadIdx.x;
    const int wave = tid >> 6, lane = tid & 63;
    const int wm = wave & 1, wn = wave >> 1;
    const int col = lane & 15, row0 = (lane >> 4) << 2, kq = (lane >> 4) << 3;
    const int m0 = blockIdx.x * 128, n0 = blockIdx.y * 128;
    const int r0 = tid >> 2, c0 = (tid & 3) << 3;
    const int r1 = r0 + 64;
    f32x4 acc[4][4];
    #pragma unroll
    for (int mi = 0; mi < 4; ++mi)
        #pragma unroll
        for (int ni = 0; ni < 4; ++ni) {
            acc[mi][ni][0] = 0.f; acc[mi][ni][1] = 0.f;
            acc[mi][ni][2] = 0.f; acc[mi][ni][3] = 0.f;
        }
    for (int kt = 0; kt < 32; ++kt) {
        const int k0 = kt * 32;
        uint4 va0 = *(const uint4*)(A + (size_t)(m0 + r0) * 1024 + k0 + c0);
        uint4 vb0 = *(const uint4*)(W + (size_t)(n0 + r0) * 1024 + k0 + c0);
        uint4 va1 = *(const uint4*)(A + (size_t)(m0 + r1) * 1024 + k0 + c0);
        uint4 vb1 = *(const uint4*)(W + (size_t)(n0 + r1) * 1024 + k0 + c0);
        __syncthreads();
        *(uint4*)(a_s + r0 * 40 + c0) = va0;
        *(uint4*)(b_s + r0 * 40 + c0) = vb0;
        *(uint4*)(a_s + r1 * 40 + c0) = va1;
        *(uint4*)(b_s + r1 * 40 + c0) = vb1;
        __syncthreads();
        bf16x8 af[4], bfv[4];
        #pragma unroll
        for (int i = 0; i < 4; ++i)
            af[i] = *(const bf16x8*)(a_s + (wm * 64 + i * 16 + col) * 40 + kq);
        #pragma unroll
        for (int i = 0; i < 4; ++i)
            bfv[i] = *(const bf16x8*)(b_s + (wn * 64 + i * 16 + col) * 40 + kq);
        #pragma unroll
        for (int mi = 0; mi < 4; ++mi)
            #pragma unroll
            for (int ni = 0; ni < 4; ++ni)
                acc[mi][ni] = __builtin_amdgcn_mfma_f32_16x16x32_bf16(af[mi], bfv[ni], acc[mi][ni], 0, 0, 0);
    }
    #pragma unroll
    for (int mi = 0; mi < 4; ++mi) {
        const int mbase = m0 + wm * 64 + mi * 16;
        const int t = mbase >> 5;
        const int b0 = (mbase & 31) + row0;
        #pragma unroll
        for (int ni = 0; ni < 4; ++ni) {
            const int n = n0 + wn * 64 + ni * 16 + col;
            const int gt = n >> 10, ii = n & 1023;
            const float bias = bih[n] + bhh[n];
            const size_t off = (((size_t)t * 64 + (ii >> 4)) * 48 + gt * 16 + (ii & 15)) * 32 + b0;
            f32x4 v = acc[mi][ni];
            PK4 pk;
            pk.b[0]=(bf16)(v[0]+bias); pk.b[1]=(bf16)(v[1]+bias);
            pk.b[2]=(bf16)(v[2]+bias); pk.b[3]=(bf16)(v[3]+bias);
            *(uint2*)(gx + off) = pk.u;
        }
    }
}

// ---------------- persistent recurrent kernel ----------------
// 32 WGs x 384 thr (6 waves). Wave = (glocal 0..1) x (gate 0..2); each wave
// keeps 16 weight-rows x K=1024 in 128 regs (R1 footprint) and computes BOTH
// mtiles (64 MFMAs). A WG covers 2 feature-groups -> grid coherent h-read
// halves to 2 MB/step. R1's proven flag protocol.
__global__ __launch_bounds__(384, 1) void smru_rec_kernel(
        const bf16* __restrict__ wr, const bf16* __restrict__ gx,
        const float* __restrict__ h0,
        bf16* __restrict__ hbuf, float* __restrict__ out,
        unsigned int* __restrict__ flags) {
    extern __shared__ char smem[];
    bf16* h_s = (bf16*)smem;               // 2 x 32x512 bf16 = 65536 B (swizzled)
    float* g_s = (float*)(smem + 65536);   // 12 tiles x 16x17 fp32 = 13056 B
    const int g2 = blockIdx.x;             // group pair: 2*g2, 2*g2+1
    const int tid = threadIdx.x;
    const int wave = tid >> 6, lane = tid & 63;
    const int glocal = (wave >= 3) ? 1 : 0;
    const int gate = wave - glocal * 3;    // 0..2
    const int g = g2 * 2 + glocal;
    const int col = lane & 15, row0 = (lane >> 4) << 2, kq = (lane >> 4) << 3;

    // ---- weights: B-fragment rows (gate*16+col of group g), full K=1024 ----
    bf16x8 wreg[32];
    {
        const bf16* wrow = wr + (size_t)g * 49152 + (size_t)(gate * 16 + col) * 1024 + kq;
        #pragma unroll
        for (int c2 = 0; c2 < 2; ++c2)
            #pragma unroll
            for (int kk = 0; kk < 16; ++kk)
                wreg[c2 * 16 + kk] = *(const bf16x8*)(wrow + c2 * 512 + kk * 32);
    }

    // fp32 recurrent state: 1024 elems over 384 thr, j-loop (b = s&31, ff = s>>5)
    float hreg[3];
    #pragma unroll
    for (int j = 0; j < 3; ++j) {
        int s = tid + 384 * j;
        if (j < 2 || tid < 256)
            hreg[j] = h0[(s & 31) * 1024 + g2 * 32 + (s >> 5)];
        else hreg[j] = 0.f;
    }

    const int hswz = (col & 7) * 8;        // rows col and 16+col share (r&7)

    // preload gx for t=0 (both mtiles)
    uint2 gv0 = *(const uint2*)(gx + (((size_t)0 * 64 + g) * 48 + gate * 16 + col) * 32 + row0);
    uint2 gv1 = *(const uint2*)(gx + (((size_t)0 * 64 + g) * 48 + gate * 16 + col) * 32 + 16 + row0);

    for (int t = 0; t < T_STEPS; ++t) {
        // ================= stage h_t into LDS =================
        if (t == 0) {
            #pragma unroll
            for (int j = 0; j < 11; ++j) {
                if (j < 10 || tid < 256) {
                    int s = tid + 384 * j;
                    int r = s >> 7, c8 = (s & 127) << 3;
                    float4 f0v = *(const float4*)(h0 + r * 1024 + c8);
                    float4 f1v = *(const float4*)(h0 + r * 1024 + c8 + 4);
                    PK8 pk;
                    pk.b[0]=(bf16)f0v.x; pk.b[1]=(bf16)f0v.y; pk.b[2]=(bf16)f0v.z; pk.b[3]=(bf16)f0v.w;
                    pk.b[4]=(bf16)f1v.x; pk.b[5]=(bf16)f1v.y; pk.b[6]=(bf16)f1v.z; pk.b[7]=(bf16)f1v.w;
                    int hf = c8 >> 9, cc = c8 & 511;
                    *(uint4*)(h_s + hf * 16384 + r * 512 + (cc ^ ((r & 7) * 8))) = pk.u;
                }
            }
        } else {
            const bf16* hsrc = hbuf + (size_t)(t & 1) * 32768;
            u32x4 L[11];
            #pragma unroll
            for (int j = 0; j < 11; ++j) {
                if (j < 10 || tid < 256) {
                    int s = tid + 384 * j;
                    int r = s >> 7, c8 = (s & 127) << 3;
                    const bf16* p = hsrc + r * 1024 + c8;
                    asm volatile("global_load_dwordx4 %0, %1, off sc0 sc1"
                                 : "=v"(L[j]) : "v"(p) : "memory");
                }
            }
            asm volatile("s_waitcnt vmcnt(0)" ::: "memory");
            __builtin_amdgcn_sched_barrier(0);
            #pragma unroll
            for (int j = 0; j < 11; ++j) {
                if (j < 10 || tid < 256) {
                    int s = tid + 384 * j;
                    int r = s >> 7, c8 = (s & 127) << 3;
                    int hf = c8 >> 9, cc = c8 & 511;
                    *(u32x4*)(h_s + hf * 16384 + r * 512 + (cc ^ ((r & 7) * 8))) = L[j];
                }
            }
        }

        // prefetch gx for t+1 (normal cached loads)
        uint2 gvn0, gvn1;
        {
            int tn = (t + 1 < T_STEPS) ? t + 1 : t;
            const bf16* base = gx + (((size_t)tn * 64 + g) * 48 + gate * 16 + col) * 32;
            gvn0 = *(const uint2*)(base + row0);
            gvn1 = *(const uint2*)(base + 16 + row0);
        }

        __syncthreads();   // sync A: h_s ready

        // acc init from gx; per mtile, two k-chains (chunk0 / chunk1)
        f32x4 a0A, a0B, a1A, a1B;
        {
            union { uint2 u; bf16 b[4]; } pk;
            pk.u = gv0;
            a0A[0]=(float)pk.b[0]; a0A[1]=(float)pk.b[1]; a0A[2]=(float)pk.b[2]; a0A[3]=(float)pk.b[3];
            pk.u = gv1;
            a1A[0]=(float)pk.b[0]; a1A[1]=(float)pk.b[1]; a1A[2]=(float)pk.b[2]; a1A[3]=(float)pk.b[3];
            a0B[0]=0.f; a0B[1]=0.f; a0B[2]=0.f; a0B[3]=0.f;
            a1B[0]=0.f; a1B[1]=0.f; a1B[2]=0.f; a1B[3]=0.f;
        }

        const bf16* hr0 = h_s + col * 512;            // mtile 0 row
        const bf16* hr1 = h_s + (16 + col) * 512;     // mtile 1 row
        #pragma unroll
        for (int kk = 0; kk < 16; ++kk) {             // chunk0 (k 0..511)
            int cc = (kk * 32 + kq) ^ hswz;
            bf16x8 v0 = *(const bf16x8*)(hr0 + cc);
            bf16x8 v1 = *(const bf16x8*)(hr1 + cc);
            a0A = __builtin_amdgcn_mfma_f32_16x16x32_bf16(v0, wreg[kk], a0A, 0, 0, 0);
            a1A = __builtin_amdgcn_mfma_f32_16x16x32_bf16(v1, wreg[kk], a1A, 0, 0, 0);
        }
        #pragma unroll
        for (int kk = 0; kk < 16; ++kk) {             // chunk1 (k 512..1023)
            int cc = 16384 + ((kk * 32 + kq) ^ hswz);
            bf16x8 v0 = *(const bf16x8*)(hr0 + cc);
            bf16x8 v1 = *(const bf16x8*)(hr1 + cc);
            a0B = __builtin_amdgcn_mfma_f32_16x16x32_bf16(v0, wreg[16 + kk], a0B, 0, 0, 0);
            a1B = __builtin_amdgcn_mfma_f32_16x16x32_bf16(v1, wreg[16 + kk], a1B, 0, 0, 0);
        }

        // ---- gate exchange: tile = glocal*6 + gate*2 + mtile ----
        {
            float* gw0 = g_s + (glocal * 6 + gate * 2 + 0) * 272;
            float* gw1 = g_s + (glocal * 6 + gate * 2 + 1) * 272;
            #pragma unroll
            for (int i = 0; i < 4; ++i) {
                gw0[(row0 + i) * 17 + col] = a0A[i] + a0B[i];
                gw1[(row0 + i) * 17 + col] = a1A[i] + a1B[i];
            }
        }
        __syncthreads();   // sync B

        // ---- softmax + state update + publish ----
        bf16* hdst = hbuf + (size_t)((t + 1) & 1) * 32768;
        #pragma unroll
        for (int j = 0; j < 3; ++j) {
            int s = tid + 384 * j;
            bool active = (j < 2) || (tid < 256);
            float hy = 0.f;
            int b = s & 31, ff = s >> 5;
            if (active) {
                int gl = ff >> 4, fl = ff & 15;
                int mt = b >> 4, rw = b & 15;
                int tb = gl * 6 + mt;
                const float gk = g_s[(tb + 0) * 272 + rw * 17 + fl];
                const float gf = g_s[(tb + 2) * 272 + rw * 17 + fl];
                const float ga = g_s[(tb + 4) * 272 + rw * 17 + fl];
                const float mx = fmaxf(gk, fmaxf(gf, ga));
                const float ek = __expf(gk - mx), ef = __expf(gf - mx), ea = __expf(ga - mx);
                const float inv = 1.0f / (ek + ef + ea);
                hy = ek * inv * hreg[j] + ea * inv;
                hreg[j] = hy;
            }
            union { bf16 h; unsigned short u; } cv; cv.h = (bf16)hy;
            unsigned int my = (unsigned int)cv.u;
            unsigned int nb = __shfl_down(my, 32);
            if (active && lane < 32) {     // ff even; partner lane+32 has ff+1, same b
                __hip_atomic_store((unsigned int*)(hdst + b * 1024 + g2 * 32 + ff),
                                   my | (nb << 16),
                                   __ATOMIC_RELAXED, __HIP_MEMORY_SCOPE_AGENT);
            }
            if (active)
                out[((size_t)t * 32 + b) * 1024 + g2 * 32 + ff] = hy;
        }

        // ---- release: drain coherent stores -> WG sync -> flag ----
        asm volatile("s_waitcnt vmcnt(0)" ::: "memory");
        __syncthreads();   // sync C
        if (tid == 0)
            __hip_atomic_store(flags + g2, (unsigned int)(t + 1),
                               __ATOMIC_RELAXED, __HIP_MEMORY_SCOPE_AGENT);

        gv0 = gvn0; gv1 = gvn1;

        // ---- wait: wave0 polls 32 flags; barrier releases ----
        if (t + 1 < T_STEPS) {
            const unsigned int tgt = (unsigned int)(t + 1);
            if (tid < 64) {
                for (;;) {
                    unsigned int f = __hip_atomic_load(flags + (tid & 31),
                        __ATOMIC_RELAXED, __HIP_MEMORY_SCOPE_AGENT);
                    if (__all((int)(f >= tgt))) break;
                }
            }
            __syncthreads();   // sync D
            asm volatile("" ::: "memory");
        }
    }
}

extern "C" void kernel_launch(void* const* d_in, const int* in_sizes, int n_in,
                              void* d_out, int out_size, void* d_ws, size_t ws_size,
                              hipStream_t stream) {
    const float* x   = (const float*)d_in[0];
    const float* h0  = (const float*)d_in[1];
    const float* wih = (const float*)d_in[2];
    const float* whh = (const float*)d_in[3];
    const float* bih = (const float*)d_in[4];
    const float* bhh = (const float*)d_in[5];
    float* out = (float*)d_out;
    char* ws = (char*)d_ws;
    if (ws_size < WS_NEED) return;

    bf16* xb   = (bf16*)(ws + OFF_XBF);
    bf16* wihb = (bf16*)(ws + OFF_WIHB);
    bf16* wrp  = (bf16*)(ws + OFF_WR);
    bf16* gx   = (bf16*)(ws + OFF_GX);
    bf16* hbuf = (bf16*)(ws + OFF_WIHB);                 // wihb dead after gemm
    unsigned int* flags = (unsigned int*)(ws + OFF_XBF); // xb dead after gemm

    cvt_x_kernel<<<32768, 256, 0, stream>>>(x, xb);
    cvt_w_kernel<<<6144, 256, 0, stream>>>(wih, whh, wihb, wrp);
    gemm_x_kernel<<<dim3(512, 24), 256, 0, stream>>>(xb, wihb, bih, bhh, gx);
    hipMemsetAsync(flags, 0, 128, stream);               // after gemm reads xb
    hipFuncSetAttribute((const void*)smru_rec_kernel,
                        hipFuncAttributeMaxDynamicSharedMemorySize, 78592);
    smru_rec_kernel<<<32, 384, 78592, stream>>>(wrp, gx, h0, hbuf, out, flags);
}